// Round 8
// baseline (526.114 us; speedup 1.0000x reference)
//
#include <hip/hip_runtime.h>
#include <hip/hip_fp16.h>

#define N_NODES  100000
#define N_EDGES  6400000
#define N_GRAPHS 64
#define SCAN_BS  1024
#define NRD      25024      // deg nodes/phase: u16 LDS bins (50KB), u8 write-out
#define NRA      12512      // acc1 nodes/phase: f32 LDS bins (50KB), f16 write-out

// ---------------- setup: flag detect + gacc zero -------------------------
__global__ void setup_kernel(const int* ei, int* flag, float* gacc) {
    int t = threadIdx.x;
    if (t == 0) {
        int allzero = 1;                    // int64 indices => hi dwords all 0
        for (int k = 0; k < 16; ++k)
            if (ei[2 * k + 1] != 0) allzero = 0;
        *flag = allzero ? 2 : 1;
    }
    if (t < 3 * N_GRAPHS) gacc[t] = 0.0f;
}

// ---------------- stage 1: degree, u16 LDS atomics (r5), u8 write-out ----
__global__ __launch_bounds__(SCAN_BS)
void deg_scan(const int* ei, const int* flag, int lo, unsigned char* copies) {
    constexpr int W = NRD / 2;
    __shared__ unsigned bins[W];
    for (int i = threadIdx.x; i < W; i += SCAN_BS) bins[i] = 0u;
    __syncthreads();
    const int stride = *flag;
    const int tid = blockIdx.x * SCAN_BS + threadIdx.x;
    const int nth = gridDim.x * SCAN_BS;
    if (stride == 2) {                      // int64 dst col: 2 edges / int4
        const int4* dp = (const int4*)(ei + (size_t)N_EDGES * 2);
        int q = tid;
        for (; q + nth < N_EDGES / 2; q += 2 * nth) {
            int4 v0 = dp[q], v1 = dp[q + nth];
            unsigned a0 = (unsigned)(v0.x - lo), b0 = (unsigned)(v0.z - lo);
            unsigned a1 = (unsigned)(v1.x - lo), b1 = (unsigned)(v1.z - lo);
            if (a0 < NRD) atomicAdd(&bins[a0 >> 1], 1u << (16 * (a0 & 1)));
            if (b0 < NRD) atomicAdd(&bins[b0 >> 1], 1u << (16 * (b0 & 1)));
            if (a1 < NRD) atomicAdd(&bins[a1 >> 1], 1u << (16 * (a1 & 1)));
            if (b1 < NRD) atomicAdd(&bins[b1 >> 1], 1u << (16 * (b1 & 1)));
        }
        for (; q < N_EDGES / 2; q += nth) {
            int4 v = dp[q];
            unsigned a = (unsigned)(v.x - lo), b = (unsigned)(v.z - lo);
            if (a < NRD) atomicAdd(&bins[a >> 1], 1u << (16 * (a & 1)));
            if (b < NRD) atomicAdd(&bins[b >> 1], 1u << (16 * (b & 1)));
        }
    } else {                                // int32 dst col: 4 edges / int4
        const int4* dp = (const int4*)(ei + (size_t)N_EDGES);
        for (int q = tid; q < N_EDGES / 4; q += nth) {
            int4 v = dp[q];
            unsigned a = (unsigned)(v.x - lo), b = (unsigned)(v.y - lo);
            unsigned c = (unsigned)(v.z - lo), d = (unsigned)(v.w - lo);
            if (a < NRD) atomicAdd(&bins[a >> 1], 1u << (16 * (a & 1)));
            if (b < NRD) atomicAdd(&bins[b >> 1], 1u << (16 * (b & 1)));
            if (c < NRD) atomicAdd(&bins[c >> 1], 1u << (16 * (c & 1)));
            if (d < NRD) atomicAdd(&bins[d >> 1], 1u << (16 * (d & 1)));
        }
    }
    __syncthreads();
    // write-out: 4 nodes (2 LDS words) -> 1 u32 of 4 u8 counts (max ~6 per copy)
    unsigned* my = (unsigned*)(copies + (size_t)blockIdx.x * NRD);
    for (int k = threadIdx.x; k < NRD / 4; k += SCAN_BS) {
        unsigned w0 = bins[2 * k], w1 = bins[2 * k + 1];
        my[k] = (w0 & 0xFFu) | (((w0 >> 16) & 0xFFu) << 8) |
                ((w1 & 0xFFu) << 16) | (((w1 >> 16) & 0xFFu) << 24);
    }
}

// merge C u8 copies -> dinv; wx = dinv*x, pbt = (dinv, batch)
__global__ void deg_merge(const unsigned char* copies, int C, int lo,
                          const float* x, const int* batch, const int* flag,
                          float* wx, float2* pbt) {
    __shared__ float red[256];
    int il = threadIdx.x & 63, cs = threadIdx.x >> 6;
    int i = blockIdx.x * 64 + il;
    int gi = lo + i;
    bool ok = (i < NRD) && (gi < N_NODES);
    float partial = 0.0f;
    if (ok)
        for (int c = cs; c < C; c += 4)
            partial += (float)copies[(size_t)c * NRD + i];
    red[threadIdx.x] = partial;
    __syncthreads();
    if (cs == 0 && ok) {
        float d = 1.0f + red[il] + red[64 + il] + red[128 + il] + red[192 + il];
        float di = rsqrtf(d);
        wx[gi] = di * x[gi];
        const int stride = *flag;
        pbt[gi] = make_float2(di, (float)batch[(size_t)gi * stride]);
    }
}

// ---------------- stage 2: acc1, f32 LDS atomics (r5), f16 write-out -----
__global__ __launch_bounds__(SCAN_BS)
void acc1_scan(const int* ei, const int* flag, const float* wx, int lo,
               _Float16* copies) {
    __shared__ float bins[NRA];
    for (int i = threadIdx.x; i < NRA; i += SCAN_BS) bins[i] = 0.0f;
    __syncthreads();
    const int stride = *flag;
    const int tid = blockIdx.x * SCAN_BS + threadIdx.x;
    const int nth = gridDim.x * SCAN_BS;
    if (stride == 2) {
        const int* srcp = ei;
        const int4* dp = (const int4*)(ei + (size_t)N_EDGES * 2);
        int q = tid;
        for (; q + nth < N_EDGES / 2; q += 2 * nth) {
            int4 v0 = dp[q], v1 = dp[q + nth];
            unsigned a0 = (unsigned)(v0.x - lo), b0 = (unsigned)(v0.z - lo);
            unsigned a1 = (unsigned)(v1.x - lo), b1 = (unsigned)(v1.z - lo);
            if (a0 < NRA) atomicAdd(&bins[a0], wx[srcp[(size_t)4 * q]]);
            if (b0 < NRA) atomicAdd(&bins[b0], wx[srcp[(size_t)4 * q + 2]]);
            if (a1 < NRA) atomicAdd(&bins[a1], wx[srcp[(size_t)4 * (q + nth)]]);
            if (b1 < NRA) atomicAdd(&bins[b1], wx[srcp[(size_t)4 * (q + nth) + 2]]);
        }
        for (; q < N_EDGES / 2; q += nth) {
            int4 v = dp[q];
            unsigned a = (unsigned)(v.x - lo), b = (unsigned)(v.z - lo);
            if (a < NRA) atomicAdd(&bins[a], wx[srcp[(size_t)4 * q]]);
            if (b < NRA) atomicAdd(&bins[b], wx[srcp[(size_t)4 * q + 2]]);
        }
    } else {
        const int* srcp = ei;
        const int4* dp = (const int4*)(ei + (size_t)N_EDGES);
        for (int q = tid; q < N_EDGES / 4; q += nth) {
            int4 v = dp[q];
            unsigned a = (unsigned)(v.x - lo), b = (unsigned)(v.y - lo);
            unsigned c = (unsigned)(v.z - lo), d = (unsigned)(v.w - lo);
            if (a < NRA) atomicAdd(&bins[a], wx[srcp[4 * q + 0]]);
            if (b < NRA) atomicAdd(&bins[b], wx[srcp[4 * q + 1]]);
            if (c < NRA) atomicAdd(&bins[c], wx[srcp[4 * q + 2]]);
            if (d < NRA) atomicAdd(&bins[d], wx[srcp[4 * q + 3]]);
        }
    }
    __syncthreads();
    _Float16* my = copies + (size_t)blockIdx.x * NRA;
    for (int i = threadIdx.x; i < NRA; i += SCAN_BS)
        my[i] = (_Float16)bins[i];          // single rounding of a tiny partial
}

// merge acc1 f16 copies -> py=(dinv,y1); pool self-loop terms into gacc
__global__ void acc1_merge(const _Float16* copies, int C, int lo,
                           const float* wx, const float2* pbt,
                           float2* py, float* gacc) {
    __shared__ float red[256];
    __shared__ float bins[3 * N_GRAPHS];
    int t = threadIdx.x;
    for (int k = t; k < 3 * N_GRAPHS; k += 256) bins[k] = 0.0f;
    int il = t & 63, cs = t >> 6;
    int i = blockIdx.x * 64 + il;
    int gi = lo + i;
    bool ok = (i < NRA) && (gi < N_NODES);
    float partial = 0.0f;
    if (ok)
        for (int c = cs; c < C; c += 4)
            partial += (float)copies[(size_t)c * NRA + i];
    red[t] = partial;
    __syncthreads();
    if (cs == 0 && ok) {
        float a1 = red[il] + red[64 + il] + red[128 + il] + red[192 + il];
        float2 pb = pbt[gi];
        float di = pb.x;
        float y1 = di * (a1 + wx[gi]);       // dinv*(acc1 + dinv*x)
        py[gi] = make_float2(di, y1);
        int g = (int)pb.y;
        float di2 = di * di;
        atomicAdd(&bins[g], di2 * y1);                 // Sy self-loop
        atomicAdd(&bins[N_GRAPHS + g], di2);           // Sz self-loop
        atomicAdd(&bins[2 * N_GRAPHS + g], 1.0f);      // count
    }
    __syncthreads();
    for (int k = t; k < 3 * N_GRAPHS; k += 256)
        if (bins[k] != 0.0f) atomicAdd(&gacc[k], bins[k]);
}

// ---------------- stage 3: edge pool, per-warp bins [r5 verbatim] --------
#define PW 16
__global__ __launch_bounds__(SCAN_BS)
void pool_scan(const int* ei, const int* flag, const float2* py,
               const float2* pbt, float* gacc) {
    __shared__ float wb[PW][2 * N_GRAPHS];
    int t = threadIdx.x;
    for (int k = t; k < PW * 2 * N_GRAPHS; k += SCAN_BS) ((float*)wb)[k] = 0.0f;
    __syncthreads();
    float* mb = wb[t >> 6];
    const int stride = *flag;
    const int tid = blockIdx.x * SCAN_BS + t;
    const int nth = gridDim.x * SCAN_BS;
    if (stride == 2) {
        const int4* sp = (const int4*)ei;
        const int4* dp = (const int4*)(ei + (size_t)N_EDGES * 2);
        int q = tid;
        for (; q + nth < N_EDGES / 2; q += 2 * nth) {
            int4 s0 = sp[q], d0 = dp[q], s1 = sp[q + nth], d1 = dp[q + nth];
            float2 pa0 = py[s0.x], pb0 = pbt[d0.x];
            float2 pa1 = py[s0.z], pb1 = pbt[d0.z];
            float2 pa2 = py[s1.x], pb2 = pbt[d1.x];
            float2 pa3 = py[s1.z], pb3 = pbt[d1.z];
            float w0 = pb0.x * pa0.x, w1 = pb1.x * pa1.x;
            float w2 = pb2.x * pa2.x, w3 = pb3.x * pa3.x;
            int g0 = (int)pb0.y, g1 = (int)pb1.y, g2 = (int)pb2.y, g3 = (int)pb3.y;
            atomicAdd(&mb[g0], w0 * pa0.y); atomicAdd(&mb[N_GRAPHS + g0], w0);
            atomicAdd(&mb[g1], w1 * pa1.y); atomicAdd(&mb[N_GRAPHS + g1], w1);
            atomicAdd(&mb[g2], w2 * pa2.y); atomicAdd(&mb[N_GRAPHS + g2], w2);
            atomicAdd(&mb[g3], w3 * pa3.y); atomicAdd(&mb[N_GRAPHS + g3], w3);
        }
        for (; q < N_EDGES / 2; q += nth) {
            int4 sv = sp[q], dv = dp[q];
            float2 pa0 = py[sv.x], pb0 = pbt[dv.x];
            float2 pa1 = py[sv.z], pb1 = pbt[dv.z];
            float w0 = pb0.x * pa0.x, w1 = pb1.x * pa1.x;
            int g0 = (int)pb0.y, g1 = (int)pb1.y;
            atomicAdd(&mb[g0], w0 * pa0.y); atomicAdd(&mb[N_GRAPHS + g0], w0);
            atomicAdd(&mb[g1], w1 * pa1.y); atomicAdd(&mb[N_GRAPHS + g1], w1);
        }
    } else {
        const int4* sp = (const int4*)ei;
        const int4* dp = (const int4*)(ei + (size_t)N_EDGES);
        for (int q = tid; q < N_EDGES / 4; q += nth) {
            int4 sv = sp[q], dv = dp[q];
            int ss[4] = {sv.x, sv.y, sv.z, sv.w};
            int dd[4] = {dv.x, dv.y, dv.z, dv.w};
            #pragma unroll
            for (int k = 0; k < 4; ++k) {
                float2 pa = py[ss[k]]; float2 pb = pbt[dd[k]];
                float w = pb.x * pa.x; int g = (int)pb.y;
                atomicAdd(&mb[g], w * pa.y); atomicAdd(&mb[N_GRAPHS + g], w);
            }
        }
    }
    __syncthreads();
    for (int k = t; k < 2 * N_GRAPHS; k += SCAN_BS) {
        float s = 0.0f;
        for (int w = 0; w < PW; ++w) s += wb[w][k];
        if (s != 0.0f) atomicAdd(&gacc[k], s);
    }
}

// ---------------- final --------------------------------------------------
__global__ void final_kernel(const float* W1, const float* b1, const float* W2,
                             const float* b2, const float* gacc, float* out) {
    int g = threadIdx.x;
    if (g >= N_GRAPHS) return;
    float w0 = 0.f, w1 = 0.f, c0 = 0.f, c1 = 0.f;
    for (int j = 0; j < 16; ++j) {
        float a = W2[2 * j], b = W2[2 * j + 1];
        w0 += W1[j] * a;  w1 += W1[j] * b;
        c0 += b1[j] * a;  c1 += b1[j] * b;
    }
    float sy  = gacc[g];
    float sz  = gacc[N_GRAPHS + g];
    float cnt = gacc[2 * N_GRAPHS + g];
    float inv = 1.0f / fmaxf(cnt, 1.0f);
    out[2 * g + 0] = (sy * w0 + sz * c0 + cnt * b2[0]) * inv;
    out[2 * g + 1] = (sy * w1 + sz * c1 + cnt * b2[1]) * inv;
}

extern "C" void kernel_launch(void* const* d_in, const int* in_sizes, int n_in,
                              void* d_out, int out_size, void* d_ws, size_t ws_size,
                              hipStream_t stream) {
    const float* x     = (const float*)d_in[0];
    const int*   ei    = (const int*)d_in[1];
    const int*   batch = (const int*)d_in[2];
    const float* W1    = (const float*)d_in[3];
    const float* b1    = (const float*)d_in[4];
    const float* W2    = (const float*)d_in[5];
    const float* b2    = (const float*)d_in[6];
    float* out = (float*)d_out;

    // ws: wx[N] | py[N]f2 | pbt[N]f2 | gacc[192] | flag[16] | copies...
    float*  f    = (float*)d_ws;
    float*  wx   = f;
    float2* py   = (float2*)(wx + N_NODES);
    float2* pbt  = py + N_NODES;
    float*  gacc = (float*)(pbt + N_NODES);
    int*    flag = (int*)(gacc + 3 * N_GRAPHS);
    void*   copies = (void*)(flag + 16);

    const long fixedB = (5L * N_NODES + 3 * N_GRAPHS + 16) * 4;
    long availB = (long)ws_size - fixedB;
    if (availB < 5600000) availB = 5600000;   // ws >= 7.6MB proven in r3

    // deg: u8 copies, NRD bytes per copy.  acc1: f16 copies, 2*NRA bytes.
    long CD = availB / NRD;        if (CD > 256) CD = 256; if (CD < 8) CD = 8;
    long CA = availB / (2 * NRA);  if (CA > 256) CA = 256; if (CA < 8) CA = 8;
    const int PD = (N_NODES + NRD - 1) / NRD;   // 4
    const int PA = (N_NODES + NRA - 1) / NRA;   // 8

    setup_kernel<<<1, 256, 0, stream>>>(ei, flag, gacc);

    for (int p = 0; p < PD; ++p) {
        int lo = p * NRD;
        deg_scan<<<(int)CD, SCAN_BS, 0, stream>>>(ei, flag, lo,
                                                  (unsigned char*)copies);
        int range = (N_NODES - lo < NRD) ? (N_NODES - lo) : NRD;
        deg_merge<<<(range + 63) / 64, 256, 0, stream>>>(
            (const unsigned char*)copies, (int)CD, lo, x, batch, flag, wx, pbt);
    }

    for (int p = 0; p < PA; ++p) {
        int lo = p * NRA;
        acc1_scan<<<(int)CA, SCAN_BS, 0, stream>>>(ei, flag, wx, lo,
                                                   (_Float16*)copies);
        int range = (N_NODES - lo < NRA) ? (N_NODES - lo) : NRA;
        acc1_merge<<<(range + 63) / 64, 256, 0, stream>>>(
            (const _Float16*)copies, (int)CA, lo, wx, pbt, py, gacc);
    }

    pool_scan<<<512, SCAN_BS, 0, stream>>>(ei, flag, py, pbt, gacc);
    final_kernel<<<1, 64, 0, stream>>>(W1, b1, W2, b2, gacc, out);
}

// Round 10
// 255.703 us; speedup vs baseline: 2.0575x; 2.0575x over previous
//
#include <hip/hip_runtime.h>

#define N_NODES  100000
#define N_EDGES  6400000
#define N_GRAPHS 64
#define SCAN_BS  1024
#define NR2      50048               // nodes per phase (2 phases cover 100000)
#define LDSW     (NR2 / 2)           // 25024 u32 words = 100KB LDS per scan block

// ---------------- setup: flag detect + gacc zero -------------------------
__global__ void setup_kernel(const int* ei, int* flag, float* gacc) {
    int t = threadIdx.x;
    if (t == 0) {
        int allzero = 1;                    // int64 indices => hi dwords all 0
        for (int k = 0; k < 16; ++k)
            if (ei[2 * k + 1] != 0) allzero = 0;
        *flag = allzero ? 2 : 1;
    }
    if (t < 3 * N_GRAPHS) gacc[t] = 0.0f;
}

// ---------------- stage 1: degree, u16-pair LDS bins, 4-deep unroll ------
__global__ __launch_bounds__(SCAN_BS)
void deg_scan(const int* ei, const int* flag, int lo, unsigned* copies) {
    __shared__ unsigned bins[LDSW];
    for (int i = threadIdx.x; i < LDSW; i += SCAN_BS) bins[i] = 0u;
    __syncthreads();
    const int stride = *flag;
    const int tid = blockIdx.x * SCAN_BS + threadIdx.x;
    const int nth = gridDim.x * SCAN_BS;
#define DEGADD(u) { unsigned a = (unsigned)((u) - lo); \
    if (a < NR2) atomicAdd(&bins[a >> 1], 1u << (16 * (a & 1))); }
    if (stride == 2) {                      // int64 dst col: 2 edges / int4
        const int4* dp = (const int4*)(ei + (size_t)N_EDGES * 2);
        const int lim = N_EDGES / 2;
        int q = tid;
        for (; q + 3 * nth < lim; q += 4 * nth) {
            int4 v0 = dp[q], v1 = dp[q + nth];
            int4 v2 = dp[q + 2 * nth], v3 = dp[q + 3 * nth];
            DEGADD(v0.x); DEGADD(v0.z); DEGADD(v1.x); DEGADD(v1.z);
            DEGADD(v2.x); DEGADD(v2.z); DEGADD(v3.x); DEGADD(v3.z);
        }
        for (; q < lim; q += nth) { int4 v = dp[q]; DEGADD(v.x); DEGADD(v.z); }
    } else {                                // int32 dst col: 4 edges / int4
        const int4* dp = (const int4*)(ei + (size_t)N_EDGES);
        for (int q = tid; q < N_EDGES / 4; q += nth) {
            int4 v = dp[q];
            DEGADD(v.x); DEGADD(v.y); DEGADD(v.z); DEGADD(v.w);
        }
    }
#undef DEGADD
    __syncthreads();
    unsigned* my = copies + (size_t)blockIdx.x * LDSW;
    for (int i = threadIdx.x; i < LDSW; i += SCAN_BS) my[i] = bins[i];
}

// merge C u16-pair copies -> dinv; wx = dinv*x, pbt = (dinv, batch)  [r5]
__global__ void deg_merge(const unsigned* copies, int C, int lo,
                          const float* x, const int* batch, const int* flag,
                          float* wx, float2* pbt) {
    __shared__ float red[256];
    int il = threadIdx.x & 63, cs = threadIdx.x >> 6;
    int i = blockIdx.x * 64 + il;
    int gi = lo + i;
    bool ok = (i < NR2) && (gi < N_NODES);
    float partial = 0.0f;
    if (ok) {
        int sh = 16 * (i & 1), w = i >> 1;
        for (int c = cs; c < C; c += 4)
            partial += (float)((copies[(size_t)c * LDSW + w] >> sh) & 0xFFFFu);
    }
    red[threadIdx.x] = partial;
    __syncthreads();
    if (cs == 0 && ok) {
        float d = 1.0f + red[il] + red[64 + il] + red[128 + il] + red[192 + il];
        float di = rsqrtf(d);
        wx[gi] = di * x[gi];
        const int stride = *flag;
        pbt[gi] = make_float2(di, (float)batch[(size_t)gi * stride]);
    }
}

// ---------------- stage 2: acc1, f16-pair LDS bins via ds_pk_add_f16 -----
__device__ __forceinline__ void pk_add_f16(unsigned ldsBase, unsigned a, float v) {
    _Float16 h = (_Float16)v;
    unsigned hb = (unsigned)__builtin_bit_cast(unsigned short, h);
    unsigned pk = (a & 1) ? (hb << 16) : hb;
    unsigned addr = ldsBase + ((a >> 1) << 2);
    asm volatile("ds_pk_add_f16 %0, %1" :: "v"(addr), "v"(pk) : "memory");
}

__global__ __launch_bounds__(SCAN_BS)
void acc1_scan(const int* ei, const int* flag, const float* wx, int lo,
               unsigned* copies) {
    __shared__ unsigned bins[LDSW];         // 2 x f16 per word, +0 initialized
    for (int i = threadIdx.x; i < LDSW; i += SCAN_BS) bins[i] = 0u;
    __syncthreads();
    const unsigned ldsBase = (unsigned)(uintptr_t)&bins[0];  // low 32b = LDS offset
    const int stride = *flag;
    const int tid = blockIdx.x * SCAN_BS + threadIdx.x;
    const int nth = gridDim.x * SCAN_BS;
    if (stride == 2) {
        const int* srcp = ei;
        const int4* dp = (const int4*)(ei + (size_t)N_EDGES * 2);
        const int lim = N_EDGES / 2;
        int q = tid;
        for (; q + 3 * nth < lim; q += 4 * nth) {
            int4 v0 = dp[q], v1 = dp[q + nth];
            int4 v2 = dp[q + 2 * nth], v3 = dp[q + 3 * nth];
            unsigned a0 = (unsigned)(v0.x - lo), a1 = (unsigned)(v0.z - lo);
            unsigned a2 = (unsigned)(v1.x - lo), a3 = (unsigned)(v1.z - lo);
            unsigned a4 = (unsigned)(v2.x - lo), a5 = (unsigned)(v2.z - lo);
            unsigned a6 = (unsigned)(v3.x - lo), a7 = (unsigned)(v3.z - lo);
            // hoist gathers: masked src-idx loads, then wx loads (clamped idx 0)
            int s0 = 0, s1 = 0, s2 = 0, s3 = 0, s4 = 0, s5 = 0, s6 = 0, s7 = 0;
            if (a0 < NR2) s0 = srcp[(size_t)4 * q];
            if (a1 < NR2) s1 = srcp[(size_t)4 * q + 2];
            if (a2 < NR2) s2 = srcp[(size_t)4 * (q + nth)];
            if (a3 < NR2) s3 = srcp[(size_t)4 * (q + nth) + 2];
            if (a4 < NR2) s4 = srcp[(size_t)4 * (q + 2 * nth)];
            if (a5 < NR2) s5 = srcp[(size_t)4 * (q + 2 * nth) + 2];
            if (a6 < NR2) s6 = srcp[(size_t)4 * (q + 3 * nth)];
            if (a7 < NR2) s7 = srcp[(size_t)4 * (q + 3 * nth) + 2];
            float w0 = wx[s0], w1 = wx[s1], w2 = wx[s2], w3 = wx[s3];
            float w4 = wx[s4], w5 = wx[s5], w6 = wx[s6], w7 = wx[s7];
            if (a0 < NR2) pk_add_f16(ldsBase, a0, w0);
            if (a1 < NR2) pk_add_f16(ldsBase, a1, w1);
            if (a2 < NR2) pk_add_f16(ldsBase, a2, w2);
            if (a3 < NR2) pk_add_f16(ldsBase, a3, w3);
            if (a4 < NR2) pk_add_f16(ldsBase, a4, w4);
            if (a5 < NR2) pk_add_f16(ldsBase, a5, w5);
            if (a6 < NR2) pk_add_f16(ldsBase, a6, w6);
            if (a7 < NR2) pk_add_f16(ldsBase, a7, w7);
        }
        for (; q < lim; q += nth) {
            int4 v = dp[q];
            unsigned a = (unsigned)(v.x - lo), b = (unsigned)(v.z - lo);
            if (a < NR2) pk_add_f16(ldsBase, a, wx[srcp[(size_t)4 * q]]);
            if (b < NR2) pk_add_f16(ldsBase, b, wx[srcp[(size_t)4 * q + 2]]);
        }
    } else {
        const int* srcp = ei;
        const int4* dp = (const int4*)(ei + (size_t)N_EDGES);
        for (int q = tid; q < N_EDGES / 4; q += nth) {
            int4 v = dp[q];
            unsigned a = (unsigned)(v.x - lo), b = (unsigned)(v.y - lo);
            unsigned c = (unsigned)(v.z - lo), d = (unsigned)(v.w - lo);
            if (a < NR2) pk_add_f16(ldsBase, a, wx[srcp[4 * q + 0]]);
            if (b < NR2) pk_add_f16(ldsBase, b, wx[srcp[4 * q + 1]]);
            if (c < NR2) pk_add_f16(ldsBase, c, wx[srcp[4 * q + 2]]);
            if (d < NR2) pk_add_f16(ldsBase, d, wx[srcp[4 * q + 3]]);
        }
    }
    __syncthreads();
    unsigned* my = copies + (size_t)blockIdx.x * LDSW;
    for (int i = threadIdx.x; i < LDSW; i += SCAN_BS) my[i] = bins[i];
}

// merge acc1 f16-pair copies -> py=(dinv,y1); pool self-loop terms into gacc
__global__ void acc1_merge(const unsigned* copies, int C, int lo,
                           const float* wx, const float2* pbt,
                           float2* py, float* gacc) {
    __shared__ float red[256];
    __shared__ float bins[3 * N_GRAPHS];
    int t = threadIdx.x;
    for (int k = t; k < 3 * N_GRAPHS; k += 256) bins[k] = 0.0f;
    int il = t & 63, cs = t >> 6;
    int i = blockIdx.x * 64 + il;
    int gi = lo + i;
    bool ok = (i < NR2) && (gi < N_NODES);
    float partial = 0.0f;
    if (ok) {
        int sh = 16 * (i & 1), w = i >> 1;
        for (int c = cs; c < C; c += 4) {
            unsigned u = (copies[(size_t)c * LDSW + w] >> sh) & 0xFFFFu;
            partial += (float)__builtin_bit_cast(_Float16, (unsigned short)u);
        }
    }
    red[t] = partial;
    __syncthreads();
    if (cs == 0 && ok) {
        float a1 = red[il] + red[64 + il] + red[128 + il] + red[192 + il];
        float2 pb = pbt[gi];
        float di = pb.x;
        float y1 = di * (a1 + wx[gi]);       // dinv*(acc1 + dinv*x)
        py[gi] = make_float2(di, y1);
        int g = (int)pb.y;
        float di2 = di * di;
        atomicAdd(&bins[g], di2 * y1);                 // Sy self-loop
        atomicAdd(&bins[N_GRAPHS + g], di2);           // Sz self-loop
        atomicAdd(&bins[2 * N_GRAPHS + g], 1.0f);      // count
    }
    __syncthreads();
    for (int k = t; k < 3 * N_GRAPHS; k += 256)
        if (bins[k] != 0.0f) atomicAdd(&gacc[k], bins[k]);
}

// ---------------- stage 3: edge pool, per-warp bins [r5 verbatim] --------
#define PW 16
__global__ __launch_bounds__(SCAN_BS)
void pool_scan(const int* ei, const int* flag, const float2* py,
               const float2* pbt, float* gacc) {
    __shared__ float wb[PW][2 * N_GRAPHS];
    int t = threadIdx.x;
    for (int k = t; k < PW * 2 * N_GRAPHS; k += SCAN_BS) ((float*)wb)[k] = 0.0f;
    __syncthreads();
    float* mb = wb[t >> 6];
    const int stride = *flag;
    const int tid = blockIdx.x * SCAN_BS + t;
    const int nth = gridDim.x * SCAN_BS;
    if (stride == 2) {
        const int4* sp = (const int4*)ei;
        const int4* dp = (const int4*)(ei + (size_t)N_EDGES * 2);
        int q = tid;
        for (; q + nth < N_EDGES / 2; q += 2 * nth) {
            int4 s0 = sp[q], d0 = dp[q], s1 = sp[q + nth], d1 = dp[q + nth];
            float2 pa0 = py[s0.x], pb0 = pbt[d0.x];
            float2 pa1 = py[s0.z], pb1 = pbt[d0.z];
            float2 pa2 = py[s1.x], pb2 = pbt[d1.x];
            float2 pa3 = py[s1.z], pb3 = pbt[d1.z];
            float w0 = pb0.x * pa0.x, w1 = pb1.x * pa1.x;
            float w2 = pb2.x * pa2.x, w3 = pb3.x * pa3.x;
            int g0 = (int)pb0.y, g1 = (int)pb1.y, g2 = (int)pb2.y, g3 = (int)pb3.y;
            atomicAdd(&mb[g0], w0 * pa0.y); atomicAdd(&mb[N_GRAPHS + g0], w0);
            atomicAdd(&mb[g1], w1 * pa1.y); atomicAdd(&mb[N_GRAPHS + g1], w1);
            atomicAdd(&mb[g2], w2 * pa2.y); atomicAdd(&mb[N_GRAPHS + g2], w2);
            atomicAdd(&mb[g3], w3 * pa3.y); atomicAdd(&mb[N_GRAPHS + g3], w3);
        }
        for (; q < N_EDGES / 2; q += nth) {
            int4 sv = sp[q], dv = dp[q];
            float2 pa0 = py[sv.x], pb0 = pbt[dv.x];
            float2 pa1 = py[sv.z], pb1 = pbt[dv.z];
            float w0 = pb0.x * pa0.x, w1 = pb1.x * pa1.x;
            int g0 = (int)pb0.y, g1 = (int)pb1.y;
            atomicAdd(&mb[g0], w0 * pa0.y); atomicAdd(&mb[N_GRAPHS + g0], w0);
            atomicAdd(&mb[g1], w1 * pa1.y); atomicAdd(&mb[N_GRAPHS + g1], w1);
        }
    } else {
        const int4* sp = (const int4*)ei;
        const int4* dp = (const int4*)(ei + (size_t)N_EDGES);
        for (int q = tid; q < N_EDGES / 4; q += nth) {
            int4 sv = sp[q], dv = dp[q];
            int ss[4] = {sv.x, sv.y, sv.z, sv.w};
            int dd[4] = {dv.x, dv.y, dv.z, dv.w};
            #pragma unroll
            for (int k = 0; k < 4; ++k) {
                float2 pa = py[ss[k]]; float2 pb = pbt[dd[k]];
                float w = pb.x * pa.x; int g = (int)pb.y;
                atomicAdd(&mb[g], w * pa.y); atomicAdd(&mb[N_GRAPHS + g], w);
            }
        }
    }
    __syncthreads();
    for (int k = t; k < 2 * N_GRAPHS; k += SCAN_BS) {
        float s = 0.0f;
        for (int w = 0; w < PW; ++w) s += wb[w][k];
        if (s != 0.0f) atomicAdd(&gacc[k], s);
    }
}

// ---------------- final --------------------------------------------------
__global__ void final_kernel(const float* W1, const float* b1, const float* W2,
                             const float* b2, const float* gacc, float* out) {
    int g = threadIdx.x;
    if (g >= N_GRAPHS) return;
    float w0 = 0.f, w1 = 0.f, c0 = 0.f, c1 = 0.f;
    for (int j = 0; j < 16; ++j) {
        float a = W2[2 * j], b = W2[2 * j + 1];
        w0 += W1[j] * a;  w1 += W1[j] * b;
        c0 += b1[j] * a;  c1 += b1[j] * b;
    }
    float sy  = gacc[g];
    float sz  = gacc[N_GRAPHS + g];
    float cnt = gacc[2 * N_GRAPHS + g];
    float inv = 1.0f / fmaxf(cnt, 1.0f);
    out[2 * g + 0] = (sy * w0 + sz * c0 + cnt * b2[0]) * inv;
    out[2 * g + 1] = (sy * w1 + sz * c1 + cnt * b2[1]) * inv;
}

extern "C" void kernel_launch(void* const* d_in, const int* in_sizes, int n_in,
                              void* d_out, int out_size, void* d_ws, size_t ws_size,
                              hipStream_t stream) {
    const float* x     = (const float*)d_in[0];
    const int*   ei    = (const int*)d_in[1];
    const int*   batch = (const int*)d_in[2];
    const float* W1    = (const float*)d_in[3];
    const float* b1    = (const float*)d_in[4];
    const float* W2    = (const float*)d_in[5];
    const float* b2    = (const float*)d_in[6];
    float* out = (float*)d_out;

    // ws: wx[N] | py[N]f2 | pbt[N]f2 | gacc[192] | flag[16] | copies (C x 100KB)
    float*  f    = (float*)d_ws;
    float*  wx   = f;
    float2* py   = (float2*)(wx + N_NODES);
    float2* pbt  = py + N_NODES;
    float*  gacc = (float*)(pbt + N_NODES);
    int*    flag = (int*)(gacc + 3 * N_GRAPHS);
    unsigned* copies = (unsigned*)(flag + 16);

    const long fixedB = (5L * N_NODES + 3 * N_GRAPHS + 16) * 4;
    long availB = (long)ws_size - fixedB;
    long C = availB / (LDSW * 4L);          // 100KB per copy, both stages
    if (C > 256) C = 256;
    if (C < 8)   C = 8;                     // ws evidence says C == 256 in practice

    setup_kernel<<<1, 256, 0, stream>>>(ei, flag, gacc);

    for (int p = 0; p < 2; ++p) {
        int lo = p * NR2;
        deg_scan<<<(int)C, SCAN_BS, 0, stream>>>(ei, flag, lo, copies);
        int range = (N_NODES - lo < NR2) ? (N_NODES - lo) : NR2;
        deg_merge<<<(range + 63) / 64, 256, 0, stream>>>(
            copies, (int)C, lo, x, batch, flag, wx, pbt);
    }

    for (int p = 0; p < 2; ++p) {
        int lo = p * NR2;
        acc1_scan<<<(int)C, SCAN_BS, 0, stream>>>(ei, flag, wx, lo, copies);
        int range = (N_NODES - lo < NR2) ? (N_NODES - lo) : NR2;
        acc1_merge<<<(range + 63) / 64, 256, 0, stream>>>(
            copies, (int)C, lo, wx, pbt, py, gacc);
    }

    pool_scan<<<512, SCAN_BS, 0, stream>>>(ei, flag, py, pbt, gacc);
    final_kernel<<<1, 64, 0, stream>>>(W1, b1, W2, b2, gacc, out);
}

// Round 11
// 170.403 us; speedup vs baseline: 3.0875x; 1.5006x over previous
//
#include <hip/hip_runtime.h>

#define N_NODES  100000
#define N_EDGES  6400000
#define N_GRAPHS 64
#define SCAN_BS  1024
#define NRDF     100096              // deg: all nodes, u8 bins = 97.75 KB LDS
#define DEGW     (NRDF / 4)          // 25024 u32 words
#define NR2      50048               // acc1: nodes per block-group
#define LDSW     (NR2 / 2)           // 25024 u32 words (f16 pairs) = 97.75 KB

// ---------------- setup: flag detect + gacc zero -------------------------
__global__ void setup_kernel(const int* ei, int* flag, float* gacc) {
    int t = threadIdx.x;
    if (t == 0) {
        int allzero = 1;                    // int64 indices => hi dwords all 0
        for (int k = 0; k < 16; ++k)
            if (ei[2 * k + 1] != 0) allzero = 0;
        *flag = allzero ? 2 : 1;
    }
    if (t < 3 * N_GRAPHS) gacc[t] = 0.0f;
}

// ---------------- stage 1: degree, ONE scan, u8-packed LDS bins ----------
__global__ __launch_bounds__(SCAN_BS)
void deg_scan(const int* ei, const int* flag, unsigned char* copies) {
    __shared__ unsigned bins[DEGW];
    for (int i = threadIdx.x; i < DEGW; i += SCAN_BS) bins[i] = 0u;
    __syncthreads();
    const int stride = *flag;
    const int tid = blockIdx.x * SCAN_BS + threadIdx.x;
    const int nth = gridDim.x * SCAN_BS;
#define DEGADD(u) { unsigned a = (unsigned)(u); \
    if (a < NRDF) atomicAdd(&bins[a >> 2], 1u << (8 * (a & 3))); }
    if (stride == 2) {                      // int64 dst col: 2 edges / int4
        const int4* dp = (const int4*)(ei + (size_t)N_EDGES * 2);
        const int lim = N_EDGES / 2;
        int q = tid;
        for (; q + 3 * nth < lim; q += 4 * nth) {
            int4 v0 = dp[q], v1 = dp[q + nth];
            int4 v2 = dp[q + 2 * nth], v3 = dp[q + 3 * nth];
            DEGADD(v0.x); DEGADD(v0.z); DEGADD(v1.x); DEGADD(v1.z);
            DEGADD(v2.x); DEGADD(v2.z); DEGADD(v3.x); DEGADD(v3.z);
        }
        for (; q < lim; q += nth) { int4 v = dp[q]; DEGADD(v.x); DEGADD(v.z); }
    } else {                                // int32 dst col: 4 edges / int4
        const int4* dp = (const int4*)(ei + (size_t)N_EDGES);
        for (int q = tid; q < N_EDGES / 4; q += nth) {
            int4 v = dp[q];
            DEGADD(v.x); DEGADD(v.y); DEGADD(v.z); DEGADD(v.w);
        }
    }
#undef DEGADD
    __syncthreads();
    unsigned* my = (unsigned*)(copies + (size_t)blockIdx.x * NRDF);
    for (int i = threadIdx.x; i < DEGW; i += SCAN_BS) my[i] = bins[i];
}

// merge C u8 copies -> dinv; wx = dinv*x, pbt = (dinv, batch)
__global__ void deg_merge(const unsigned char* copies, int C,
                          const float* x, const int* batch, const int* flag,
                          float* wx, float2* pbt) {
    __shared__ float red[256];
    int il = threadIdx.x & 63, cs = threadIdx.x >> 6;
    int gi = blockIdx.x * 64 + il;
    bool ok = (gi < N_NODES);
    float partial = 0.0f;
    if (ok)
        for (int c = cs; c < C; c += 4)
            partial += (float)copies[(size_t)c * NRDF + gi];
    red[threadIdx.x] = partial;
    __syncthreads();
    if (cs == 0 && ok) {
        float d = 1.0f + red[il] + red[64 + il] + red[128 + il] + red[192 + il];
        float di = rsqrtf(d);
        wx[gi] = di * x[gi];
        const int stride = *flag;
        pbt[gi] = make_float2(di, (float)batch[(size_t)gi * stride]);
    }
}

// ---------------- stage 2: acc1, ONE dispatch, block-group split ---------
__device__ __forceinline__ void pk_add_f16(unsigned ldsBase, unsigned a, float v) {
    _Float16 h = (_Float16)v;
    unsigned hb = (unsigned)__builtin_bit_cast(unsigned short, h);
    unsigned pk = (a & 1) ? (hb << 16) : hb;
    unsigned addr = ldsBase + ((a >> 1) << 2);
    asm volatile("ds_pk_add_f16 %0, %1" :: "v"(addr), "v"(pk) : "memory");
}

__global__ __launch_bounds__(SCAN_BS)
void acc1_scan(const int* ei, const int* flag, const float* wx, int G,
               unsigned* copies) {
    __shared__ unsigned bins[LDSW];         // 2 x f16 per word, +0 initialized
    for (int i = threadIdx.x; i < LDSW; i += SCAN_BS) bins[i] = 0u;
    __syncthreads();
    const int lo = (blockIdx.x >= G) ? NR2 : 0;   // block-group node range
    const unsigned ldsBase = (unsigned)(uintptr_t)&bins[0];
    const int stride = *flag;
    const int tid = blockIdx.x * SCAN_BS + threadIdx.x;
    const int nth = gridDim.x * SCAN_BS;
    if (stride == 2) {
        const int* srcp = ei;
        const int4* dp = (const int4*)(ei + (size_t)N_EDGES * 2);
        const int lim = N_EDGES / 2;
        int q = tid;
        for (; q + 3 * nth < lim; q += 4 * nth) {
            int4 v0 = dp[q], v1 = dp[q + nth];
            int4 v2 = dp[q + 2 * nth], v3 = dp[q + 3 * nth];
            unsigned a0 = (unsigned)(v0.x - lo), a1 = (unsigned)(v0.z - lo);
            unsigned a2 = (unsigned)(v1.x - lo), a3 = (unsigned)(v1.z - lo);
            unsigned a4 = (unsigned)(v2.x - lo), a5 = (unsigned)(v2.z - lo);
            unsigned a6 = (unsigned)(v3.x - lo), a7 = (unsigned)(v3.z - lo);
            int s0 = 0, s1 = 0, s2 = 0, s3 = 0, s4 = 0, s5 = 0, s6 = 0, s7 = 0;
            if (a0 < NR2) s0 = srcp[(size_t)4 * q];
            if (a1 < NR2) s1 = srcp[(size_t)4 * q + 2];
            if (a2 < NR2) s2 = srcp[(size_t)4 * (q + nth)];
            if (a3 < NR2) s3 = srcp[(size_t)4 * (q + nth) + 2];
            if (a4 < NR2) s4 = srcp[(size_t)4 * (q + 2 * nth)];
            if (a5 < NR2) s5 = srcp[(size_t)4 * (q + 2 * nth) + 2];
            if (a6 < NR2) s6 = srcp[(size_t)4 * (q + 3 * nth)];
            if (a7 < NR2) s7 = srcp[(size_t)4 * (q + 3 * nth) + 2];
            float w0 = wx[s0], w1 = wx[s1], w2 = wx[s2], w3 = wx[s3];
            float w4 = wx[s4], w5 = wx[s5], w6 = wx[s6], w7 = wx[s7];
            if (a0 < NR2) pk_add_f16(ldsBase, a0, w0);
            if (a1 < NR2) pk_add_f16(ldsBase, a1, w1);
            if (a2 < NR2) pk_add_f16(ldsBase, a2, w2);
            if (a3 < NR2) pk_add_f16(ldsBase, a3, w3);
            if (a4 < NR2) pk_add_f16(ldsBase, a4, w4);
            if (a5 < NR2) pk_add_f16(ldsBase, a5, w5);
            if (a6 < NR2) pk_add_f16(ldsBase, a6, w6);
            if (a7 < NR2) pk_add_f16(ldsBase, a7, w7);
        }
        for (; q < lim; q += nth) {
            int4 v = dp[q];
            unsigned a = (unsigned)(v.x - lo), b = (unsigned)(v.z - lo);
            if (a < NR2) pk_add_f16(ldsBase, a, wx[srcp[(size_t)4 * q]]);
            if (b < NR2) pk_add_f16(ldsBase, b, wx[srcp[(size_t)4 * q + 2]]);
        }
    } else {
        const int* srcp = ei;
        const int4* dp = (const int4*)(ei + (size_t)N_EDGES);
        for (int q = tid; q < N_EDGES / 4; q += nth) {
            int4 v = dp[q];
            unsigned a = (unsigned)(v.x - lo), b = (unsigned)(v.y - lo);
            unsigned c = (unsigned)(v.z - lo), d = (unsigned)(v.w - lo);
            if (a < NR2) pk_add_f16(ldsBase, a, wx[srcp[4 * q + 0]]);
            if (b < NR2) pk_add_f16(ldsBase, b, wx[srcp[4 * q + 1]]);
            if (c < NR2) pk_add_f16(ldsBase, c, wx[srcp[4 * q + 2]]);
            if (d < NR2) pk_add_f16(ldsBase, d, wx[srcp[4 * q + 3]]);
        }
    }
    __syncthreads();
    unsigned* my = copies + (size_t)blockIdx.x * LDSW;
    for (int i = threadIdx.x; i < LDSW; i += SCAN_BS) my[i] = bins[i];
}

// merge acc1 f16 copies (per-group) -> py=(dinv,y1); self-loop pool -> gacc
__global__ void acc1_merge(const unsigned* copies, int G,
                           const float* wx, const float2* pbt,
                           float2* py, float* gacc) {
    __shared__ float red[256];
    __shared__ float bins[3 * N_GRAPHS];
    int t = threadIdx.x;
    for (int k = t; k < 3 * N_GRAPHS; k += 256) bins[k] = 0.0f;
    int il = t & 63, cs = t >> 6;
    int gi = blockIdx.x * 64 + il;
    bool ok = (gi < N_NODES);
    float partial = 0.0f;
    int grp = (gi >= NR2) ? 1 : 0;
    int li  = gi - grp * NR2;
    if (ok) {
        int sh = 16 * (li & 1), w = li >> 1;
        const unsigned* base = copies + (size_t)grp * G * LDSW;
        for (int c = cs; c < G; c += 4) {
            unsigned u = (base[(size_t)c * LDSW + w] >> sh) & 0xFFFFu;
            partial += (float)__builtin_bit_cast(_Float16, (unsigned short)u);
        }
    }
    red[t] = partial;
    __syncthreads();
    if (cs == 0 && ok) {
        float a1 = red[il] + red[64 + il] + red[128 + il] + red[192 + il];
        float2 pb = pbt[gi];
        float di = pb.x;
        float y1 = di * (a1 + wx[gi]);       // dinv*(acc1 + dinv*x)
        py[gi] = make_float2(di, y1);
        int g = (int)pb.y;
        float di2 = di * di;
        atomicAdd(&bins[g], di2 * y1);                 // Sy self-loop
        atomicAdd(&bins[N_GRAPHS + g], di2);           // Sz self-loop
        atomicAdd(&bins[2 * N_GRAPHS + g], 1.0f);      // count
    }
    __syncthreads();
    for (int k = t; k < 3 * N_GRAPHS; k += 256)
        if (bins[k] != 0.0f) atomicAdd(&gacc[k], bins[k]);
}

// ---------------- stage 3: edge pool, per-warp bins [r5 verbatim] --------
#define PW 16
__global__ __launch_bounds__(SCAN_BS)
void pool_scan(const int* ei, const int* flag, const float2* py,
               const float2* pbt, float* gacc) {
    __shared__ float wb[PW][2 * N_GRAPHS];
    int t = threadIdx.x;
    for (int k = t; k < PW * 2 * N_GRAPHS; k += SCAN_BS) ((float*)wb)[k] = 0.0f;
    __syncthreads();
    float* mb = wb[t >> 6];
    const int stride = *flag;
    const int tid = blockIdx.x * SCAN_BS + t;
    const int nth = gridDim.x * SCAN_BS;
    if (stride == 2) {
        const int4* sp = (const int4*)ei;
        const int4* dp = (const int4*)(ei + (size_t)N_EDGES * 2);
        int q = tid;
        for (; q + nth < N_EDGES / 2; q += 2 * nth) {
            int4 s0 = sp[q], d0 = dp[q], s1 = sp[q + nth], d1 = dp[q + nth];
            float2 pa0 = py[s0.x], pb0 = pbt[d0.x];
            float2 pa1 = py[s0.z], pb1 = pbt[d0.z];
            float2 pa2 = py[s1.x], pb2 = pbt[d1.x];
            float2 pa3 = py[s1.z], pb3 = pbt[d1.z];
            float w0 = pb0.x * pa0.x, w1 = pb1.x * pa1.x;
            float w2 = pb2.x * pa2.x, w3 = pb3.x * pa3.x;
            int g0 = (int)pb0.y, g1 = (int)pb1.y, g2 = (int)pb2.y, g3 = (int)pb3.y;
            atomicAdd(&mb[g0], w0 * pa0.y); atomicAdd(&mb[N_GRAPHS + g0], w0);
            atomicAdd(&mb[g1], w1 * pa1.y); atomicAdd(&mb[N_GRAPHS + g1], w1);
            atomicAdd(&mb[g2], w2 * pa2.y); atomicAdd(&mb[N_GRAPHS + g2], w2);
            atomicAdd(&mb[g3], w3 * pa3.y); atomicAdd(&mb[N_GRAPHS + g3], w3);
        }
        for (; q < N_EDGES / 2; q += nth) {
            int4 sv = sp[q], dv = dp[q];
            float2 pa0 = py[sv.x], pb0 = pbt[dv.x];
            float2 pa1 = py[sv.z], pb1 = pbt[dv.z];
            float w0 = pb0.x * pa0.x, w1 = pb1.x * pa1.x;
            int g0 = (int)pb0.y, g1 = (int)pb1.y;
            atomicAdd(&mb[g0], w0 * pa0.y); atomicAdd(&mb[N_GRAPHS + g0], w0);
            atomicAdd(&mb[g1], w1 * pa1.y); atomicAdd(&mb[N_GRAPHS + g1], w1);
        }
    } else {
        const int4* sp = (const int4*)ei;
        const int4* dp = (const int4*)(ei + (size_t)N_EDGES);
        for (int q = tid; q < N_EDGES / 4; q += nth) {
            int4 sv = sp[q], dv = dp[q];
            int ss[4] = {sv.x, sv.y, sv.z, sv.w};
            int dd[4] = {dv.x, dv.y, dv.z, dv.w};
            #pragma unroll
            for (int k = 0; k < 4; ++k) {
                float2 pa = py[ss[k]]; float2 pb = pbt[dd[k]];
                float w = pb.x * pa.x; int g = (int)pb.y;
                atomicAdd(&mb[g], w * pa.y); atomicAdd(&mb[N_GRAPHS + g], w);
            }
        }
    }
    __syncthreads();
    for (int k = t; k < 2 * N_GRAPHS; k += SCAN_BS) {
        float s = 0.0f;
        for (int w = 0; w < PW; ++w) s += wb[w][k];
        if (s != 0.0f) atomicAdd(&gacc[k], s);
    }
}

// ---------------- final --------------------------------------------------
__global__ void final_kernel(const float* W1, const float* b1, const float* W2,
                             const float* b2, const float* gacc, float* out) {
    int g = threadIdx.x;
    if (g >= N_GRAPHS) return;
    float w0 = 0.f, w1 = 0.f, c0 = 0.f, c1 = 0.f;
    for (int j = 0; j < 16; ++j) {
        float a = W2[2 * j], b = W2[2 * j + 1];
        w0 += W1[j] * a;  w1 += W1[j] * b;
        c0 += b1[j] * a;  c1 += b1[j] * b;
    }
    float sy  = gacc[g];
    float sz  = gacc[N_GRAPHS + g];
    float cnt = gacc[2 * N_GRAPHS + g];
    float inv = 1.0f / fmaxf(cnt, 1.0f);
    out[2 * g + 0] = (sy * w0 + sz * c0 + cnt * b2[0]) * inv;
    out[2 * g + 1] = (sy * w1 + sz * c1 + cnt * b2[1]) * inv;
}

extern "C" void kernel_launch(void* const* d_in, const int* in_sizes, int n_in,
                              void* d_out, int out_size, void* d_ws, size_t ws_size,
                              hipStream_t stream) {
    const float* x     = (const float*)d_in[0];
    const int*   ei    = (const int*)d_in[1];
    const int*   batch = (const int*)d_in[2];
    const float* W1    = (const float*)d_in[3];
    const float* b1    = (const float*)d_in[4];
    const float* W2    = (const float*)d_in[5];
    const float* b2    = (const float*)d_in[6];
    float* out = (float*)d_out;

    // ws: wx[N] | py[N]f2 | pbt[N]f2 | gacc[192] | flag[16] | copies (~25.6MB)
    float*  f    = (float*)d_ws;
    float*  wx   = f;
    float2* py   = (float2*)(wx + N_NODES);
    float2* pbt  = py + N_NODES;
    float*  gacc = (float*)(pbt + N_NODES);
    int*    flag = (int*)(gacc + 3 * N_GRAPHS);
    unsigned* copies = (unsigned*)(flag + 16);

    const long fixedB = (5L * N_NODES + 3 * N_GRAPHS + 16) * 4;
    long availB = (long)ws_size - fixedB;
    long CD = availB / NRDF;                // deg: u8 copies, NRDF bytes each
    if (CD > 256) CD = 256; if (CD < 8) CD = 8;
    long G = availB / (2L * LDSW * 4);      // acc1: f16 copies per group
    if (G > 128) G = 128; if (G < 4) G = 4;

    setup_kernel<<<1, 256, 0, stream>>>(ei, flag, gacc);

    deg_scan<<<(int)CD, SCAN_BS, 0, stream>>>(ei, flag, (unsigned char*)copies);
    deg_merge<<<(N_NODES + 63) / 64, 256, 0, stream>>>(
        (const unsigned char*)copies, (int)CD, x, batch, flag, wx, pbt);

    acc1_scan<<<(int)(2 * G), SCAN_BS, 0, stream>>>(ei, flag, wx, (int)G, copies);
    acc1_merge<<<(N_NODES + 63) / 64, 256, 0, stream>>>(
        copies, (int)G, wx, pbt, py, gacc);

    pool_scan<<<512, SCAN_BS, 0, stream>>>(ei, flag, py, pbt, gacc);
    final_kernel<<<1, 64, 0, stream>>>(W1, b1, W2, b2, gacc, out);
}

// Round 12
// 168.163 us; speedup vs baseline: 3.1286x; 1.0133x over previous
//
#include <hip/hip_runtime.h>

#define N_NODES  100000
#define N_EDGES  6400000
#define N_GRAPHS 64
#define SCAN_BS  1024
#define NRDF     100096              // deg: all nodes, u8 bins = 97.75 KB LDS
#define DEGW     (NRDF / 4)          // 25024 u32 words
#define NR2      50048               // acc1: nodes per block-group (2 groups)
#define LDSW     (NR2 / 2)           // 25024 u32 words (f16 pairs) = 97.75 KB
#define NR3      33344               // acc2: nodes per block-group (3 groups), 130.25 KB LDS

// ---------------- setup: flag detect + gacc zero -------------------------
__global__ void setup_kernel(const int* ei, int* flag, float* gacc) {
    int t = threadIdx.x;
    if (t == 0) {
        int allzero = 1;                    // int64 indices => hi dwords all 0
        for (int k = 0; k < 16; ++k)
            if (ei[2 * k + 1] != 0) allzero = 0;
        *flag = allzero ? 2 : 1;
    }
    if (t < 3 * N_GRAPHS) gacc[t] = 0.0f;
}

// ---------------- stage 1: degree, ONE scan, u8-packed LDS bins ----------
__global__ __launch_bounds__(SCAN_BS)
void deg_scan(const int* ei, const int* flag, unsigned char* copies) {
    __shared__ unsigned bins[DEGW];
    for (int i = threadIdx.x; i < DEGW; i += SCAN_BS) bins[i] = 0u;
    __syncthreads();
    const int stride = *flag;
    const int tid = blockIdx.x * SCAN_BS + threadIdx.x;
    const int nth = gridDim.x * SCAN_BS;
#define DEGADD(u) { unsigned a = (unsigned)(u); \
    if (a < NRDF) atomicAdd(&bins[a >> 2], 1u << (8 * (a & 3))); }
    if (stride == 2) {                      // int64 dst col: 2 edges / int4
        const int4* dp = (const int4*)(ei + (size_t)N_EDGES * 2);
        const int lim = N_EDGES / 2;
        int q = tid;
        for (; q + 3 * nth < lim; q += 4 * nth) {
            int4 v0 = dp[q], v1 = dp[q + nth];
            int4 v2 = dp[q + 2 * nth], v3 = dp[q + 3 * nth];
            DEGADD(v0.x); DEGADD(v0.z); DEGADD(v1.x); DEGADD(v1.z);
            DEGADD(v2.x); DEGADD(v2.z); DEGADD(v3.x); DEGADD(v3.z);
        }
        for (; q < lim; q += nth) { int4 v = dp[q]; DEGADD(v.x); DEGADD(v.z); }
    } else {                                // int32 dst col: 4 edges / int4
        const int4* dp = (const int4*)(ei + (size_t)N_EDGES);
        for (int q = tid; q < N_EDGES / 4; q += nth) {
            int4 v = dp[q];
            DEGADD(v.x); DEGADD(v.y); DEGADD(v.z); DEGADD(v.w);
        }
    }
#undef DEGADD
    __syncthreads();
    unsigned* my = (unsigned*)(copies + (size_t)blockIdx.x * NRDF);
    for (int i = threadIdx.x; i < DEGW; i += SCAN_BS) my[i] = bins[i];
}

// merge C u8 copies -> dinv; wx = dinv*x, pbt = (dinv, batch)
__global__ void deg_merge(const unsigned char* copies, int C,
                          const float* x, const int* batch, const int* flag,
                          float* wx, float2* pbt) {
    __shared__ float red[256];
    int il = threadIdx.x & 63, cs = threadIdx.x >> 6;
    int gi = blockIdx.x * 64 + il;
    bool ok = (gi < N_NODES);
    float partial = 0.0f;
    if (ok)
        for (int c = cs; c < C; c += 4)
            partial += (float)copies[(size_t)c * NRDF + gi];
    red[threadIdx.x] = partial;
    __syncthreads();
    if (cs == 0 && ok) {
        float d = 1.0f + red[il] + red[64 + il] + red[128 + il] + red[192 + il];
        float di = rsqrtf(d);
        wx[gi] = di * x[gi];
        const int stride = *flag;
        pbt[gi] = make_float2(di, (float)batch[(size_t)gi * stride]);
    }
}

// ---------------- stage 2: acc1, ONE dispatch, PER-GROUP stride ----------
__device__ __forceinline__ void pk_add_f16(unsigned ldsBase, unsigned a, float v) {
    _Float16 h = (_Float16)v;
    unsigned hb = (unsigned)__builtin_bit_cast(unsigned short, h);
    unsigned pk = (a & 1) ? (hb << 16) : hb;
    unsigned addr = ldsBase + ((a >> 1) << 2);
    asm volatile("ds_pk_add_f16 %0, %1" :: "v"(addr), "v"(pk) : "memory");
}

__global__ __launch_bounds__(SCAN_BS)
void acc1_scan(const int* ei, const int* flag, const float* wx, int G,
               unsigned* copies) {
    __shared__ unsigned bins[LDSW];         // 2 x f16 per word, +0 initialized
    for (int i = threadIdx.x; i < LDSW; i += SCAN_BS) bins[i] = 0u;
    __syncthreads();
    const int grp = (blockIdx.x >= G) ? 1 : 0;
    const int lo = grp * NR2;
    const int lb = blockIdx.x - grp * G;    // block id WITHIN group
    const unsigned ldsBase = (unsigned)(uintptr_t)&bins[0];
    const int stride = *flag;
    const int tid = lb * SCAN_BS + threadIdx.x;
    const int nth = G * SCAN_BS;            // per-group stride: group covers ALL edges
    if (stride == 2) {
        const int* srcp = ei;
        const int4* dp = (const int4*)(ei + (size_t)N_EDGES * 2);
        const int lim = N_EDGES / 2;
        int q = tid;
        for (; q + 3 * nth < lim; q += 4 * nth) {
            int4 v0 = dp[q], v1 = dp[q + nth];
            int4 v2 = dp[q + 2 * nth], v3 = dp[q + 3 * nth];
            unsigned a0 = (unsigned)(v0.x - lo), a1 = (unsigned)(v0.z - lo);
            unsigned a2 = (unsigned)(v1.x - lo), a3 = (unsigned)(v1.z - lo);
            unsigned a4 = (unsigned)(v2.x - lo), a5 = (unsigned)(v2.z - lo);
            unsigned a6 = (unsigned)(v3.x - lo), a7 = (unsigned)(v3.z - lo);
            int s0 = 0, s1 = 0, s2 = 0, s3 = 0, s4 = 0, s5 = 0, s6 = 0, s7 = 0;
            if (a0 < NR2) s0 = srcp[(size_t)4 * q];
            if (a1 < NR2) s1 = srcp[(size_t)4 * q + 2];
            if (a2 < NR2) s2 = srcp[(size_t)4 * (q + nth)];
            if (a3 < NR2) s3 = srcp[(size_t)4 * (q + nth) + 2];
            if (a4 < NR2) s4 = srcp[(size_t)4 * (q + 2 * nth)];
            if (a5 < NR2) s5 = srcp[(size_t)4 * (q + 2 * nth) + 2];
            if (a6 < NR2) s6 = srcp[(size_t)4 * (q + 3 * nth)];
            if (a7 < NR2) s7 = srcp[(size_t)4 * (q + 3 * nth) + 2];
            float w0 = wx[s0], w1 = wx[s1], w2 = wx[s2], w3 = wx[s3];
            float w4 = wx[s4], w5 = wx[s5], w6 = wx[s6], w7 = wx[s7];
            if (a0 < NR2) pk_add_f16(ldsBase, a0, w0);
            if (a1 < NR2) pk_add_f16(ldsBase, a1, w1);
            if (a2 < NR2) pk_add_f16(ldsBase, a2, w2);
            if (a3 < NR2) pk_add_f16(ldsBase, a3, w3);
            if (a4 < NR2) pk_add_f16(ldsBase, a4, w4);
            if (a5 < NR2) pk_add_f16(ldsBase, a5, w5);
            if (a6 < NR2) pk_add_f16(ldsBase, a6, w6);
            if (a7 < NR2) pk_add_f16(ldsBase, a7, w7);
        }
        for (; q < lim; q += nth) {
            int4 v = dp[q];
            unsigned a = (unsigned)(v.x - lo), b = (unsigned)(v.z - lo);
            if (a < NR2) pk_add_f16(ldsBase, a, wx[srcp[(size_t)4 * q]]);
            if (b < NR2) pk_add_f16(ldsBase, b, wx[srcp[(size_t)4 * q + 2]]);
        }
    } else {
        const int* srcp = ei;
        const int4* dp = (const int4*)(ei + (size_t)N_EDGES);
        for (int q = tid; q < N_EDGES / 4; q += nth) {
            int4 v = dp[q];
            unsigned a = (unsigned)(v.x - lo), b = (unsigned)(v.y - lo);
            unsigned c = (unsigned)(v.z - lo), d = (unsigned)(v.w - lo);
            if (a < NR2) pk_add_f16(ldsBase, a, wx[srcp[4 * q + 0]]);
            if (b < NR2) pk_add_f16(ldsBase, b, wx[srcp[4 * q + 1]]);
            if (c < NR2) pk_add_f16(ldsBase, c, wx[srcp[4 * q + 2]]);
            if (d < NR2) pk_add_f16(ldsBase, d, wx[srcp[4 * q + 3]]);
        }
    }
    __syncthreads();
    unsigned* my = copies + (size_t)blockIdx.x * LDSW;
    for (int i = threadIdx.x; i < LDSW; i += SCAN_BS) my[i] = bins[i];
}

// merge acc1 copies -> y1 (f32) and pyz = packed (f16 dinv*y1, f16 dinv)
__global__ void acc1_merge(const unsigned* copies, int G,
                           const float* wx, const float2* pbt,
                           float* y1, unsigned* pyz) {
    __shared__ float red[256];
    int t = threadIdx.x;
    int il = t & 63, cs = t >> 6;
    int gi = blockIdx.x * 64 + il;
    bool ok = (gi < N_NODES);
    float partial = 0.0f;
    int grp = (gi >= NR2) ? 1 : 0;
    int li  = gi - grp * NR2;
    if (ok) {
        int sh = 16 * (li & 1), w = li >> 1;
        const unsigned* base = copies + (size_t)grp * G * LDSW;
        for (int c = cs; c < G; c += 4) {
            unsigned u = (base[(size_t)c * LDSW + w] >> sh) & 0xFFFFu;
            partial += (float)__builtin_bit_cast(_Float16, (unsigned short)u);
        }
    }
    red[t] = partial;
    __syncthreads();
    if (cs == 0 && ok) {
        float a1 = red[il] + red[64 + il] + red[128 + il] + red[192 + il];
        float di = pbt[gi].x;
        float y1v = di * (a1 + wx[gi]);      // dinv*(acc1 + dinv*x)
        y1[gi] = y1v;
        _Float16 hy = (_Float16)(di * y1v);  // wy = dinv*y1
        _Float16 hz = (_Float16)di;          // wz = dinv
        pyz[gi] = (unsigned)__builtin_bit_cast(unsigned short, hy)
                | ((unsigned)__builtin_bit_cast(unsigned short, hz) << 16);
    }
}

// ---------------- stage 3: acc2/accz scatter, 3 groups, 1 pk_add/edge ----
__global__ __launch_bounds__(SCAN_BS)
void acc2_scan(const int* ei, const int* flag, const unsigned* pyz, int G,
               unsigned* copies) {
    __shared__ unsigned bins[NR3];          // one u32 = (f16 wy-sum, f16 wz-sum)
    for (int i = threadIdx.x; i < NR3; i += SCAN_BS) bins[i] = 0u;
    __syncthreads();
    const int grp = blockIdx.x / G;         // 0,1,2
    const int lo = grp * NR3;
    const int lb = blockIdx.x - grp * G;
    const unsigned ldsBase = (unsigned)(uintptr_t)&bins[0];
    const int stride = *flag;
    const int tid = lb * SCAN_BS + threadIdx.x;
    const int nth = G * SCAN_BS;
#define PKW(addr_a, pk) asm volatile("ds_pk_add_f16 %0, %1" :: \
    "v"(ldsBase + ((addr_a) << 2)), "v"(pk) : "memory")
    if (stride == 2) {
        const int* srcp = ei;
        const int4* dp = (const int4*)(ei + (size_t)N_EDGES * 2);
        const int lim = N_EDGES / 2;
        int q = tid;
        for (; q + 3 * nth < lim; q += 4 * nth) {
            int4 v0 = dp[q], v1 = dp[q + nth];
            int4 v2 = dp[q + 2 * nth], v3 = dp[q + 3 * nth];
            unsigned a0 = (unsigned)(v0.x - lo), a1 = (unsigned)(v0.z - lo);
            unsigned a2 = (unsigned)(v1.x - lo), a3 = (unsigned)(v1.z - lo);
            unsigned a4 = (unsigned)(v2.x - lo), a5 = (unsigned)(v2.z - lo);
            unsigned a6 = (unsigned)(v3.x - lo), a7 = (unsigned)(v3.z - lo);
            int s0 = 0, s1 = 0, s2 = 0, s3 = 0, s4 = 0, s5 = 0, s6 = 0, s7 = 0;
            if (a0 < NR3) s0 = srcp[(size_t)4 * q];
            if (a1 < NR3) s1 = srcp[(size_t)4 * q + 2];
            if (a2 < NR3) s2 = srcp[(size_t)4 * (q + nth)];
            if (a3 < NR3) s3 = srcp[(size_t)4 * (q + nth) + 2];
            if (a4 < NR3) s4 = srcp[(size_t)4 * (q + 2 * nth)];
            if (a5 < NR3) s5 = srcp[(size_t)4 * (q + 2 * nth) + 2];
            if (a6 < NR3) s6 = srcp[(size_t)4 * (q + 3 * nth)];
            if (a7 < NR3) s7 = srcp[(size_t)4 * (q + 3 * nth) + 2];
            unsigned p0 = pyz[s0], p1 = pyz[s1], p2 = pyz[s2], p3 = pyz[s3];
            unsigned p4 = pyz[s4], p5 = pyz[s5], p6 = pyz[s6], p7 = pyz[s7];
            if (a0 < NR3) PKW(a0, p0);
            if (a1 < NR3) PKW(a1, p1);
            if (a2 < NR3) PKW(a2, p2);
            if (a3 < NR3) PKW(a3, p3);
            if (a4 < NR3) PKW(a4, p4);
            if (a5 < NR3) PKW(a5, p5);
            if (a6 < NR3) PKW(a6, p6);
            if (a7 < NR3) PKW(a7, p7);
        }
        for (; q < lim; q += nth) {
            int4 v = dp[q];
            unsigned a = (unsigned)(v.x - lo), b = (unsigned)(v.z - lo);
            if (a < NR3) { unsigned p = pyz[srcp[(size_t)4 * q]];     PKW(a, p); }
            if (b < NR3) { unsigned p = pyz[srcp[(size_t)4 * q + 2]]; PKW(b, p); }
        }
    } else {
        const int* srcp = ei;
        const int4* dp = (const int4*)(ei + (size_t)N_EDGES);
        for (int q = tid; q < N_EDGES / 4; q += nth) {
            int4 v = dp[q];
            unsigned a = (unsigned)(v.x - lo), b = (unsigned)(v.y - lo);
            unsigned c = (unsigned)(v.z - lo), d = (unsigned)(v.w - lo);
            if (a < NR3) { unsigned p = pyz[srcp[4 * q + 0]]; PKW(a, p); }
            if (b < NR3) { unsigned p = pyz[srcp[4 * q + 1]]; PKW(b, p); }
            if (c < NR3) { unsigned p = pyz[srcp[4 * q + 2]]; PKW(c, p); }
            if (d < NR3) { unsigned p = pyz[srcp[4 * q + 3]]; PKW(d, p); }
        }
    }
#undef PKW
    __syncthreads();
    unsigned* my = copies + (size_t)blockIdx.x * NR3;
    for (int i = threadIdx.x; i < NR3; i += SCAN_BS) my[i] = bins[i];
}

// merge acc2 copies; pool Sy/Sz/count (incl. self-loop terms) into gacc
__global__ void acc2_merge(const unsigned* copies, int G,
                           const float* y1, const float2* pbt, float* gacc) {
    __shared__ float redY[256];
    __shared__ float redZ[256];
    __shared__ float bins[3 * N_GRAPHS];
    int t = threadIdx.x;
    for (int k = t; k < 3 * N_GRAPHS; k += 256) bins[k] = 0.0f;
    int il = t & 63, cs = t >> 6;
    int gi = blockIdx.x * 64 + il;
    bool ok = (gi < N_NODES);
    float pyv = 0.0f, pzv = 0.0f;
    if (ok) {
        int grp = gi / NR3;
        int li  = gi - grp * NR3;
        const unsigned* base = copies + (size_t)grp * G * NR3;
        for (int c = cs; c < G; c += 4) {
            unsigned u = base[(size_t)c * NR3 + li];
            pyv += (float)__builtin_bit_cast(_Float16, (unsigned short)(u & 0xFFFFu));
            pzv += (float)__builtin_bit_cast(_Float16, (unsigned short)(u >> 16));
        }
    }
    redY[t] = pyv;
    redZ[t] = pzv;
    __syncthreads();
    if (cs == 0 && ok) {
        float a2 = redY[il] + redY[64 + il] + redY[128 + il] + redY[192 + il];
        float az = redZ[il] + redZ[64 + il] + redZ[128 + il] + redZ[192 + il];
        float2 pb = pbt[gi];
        float di = pb.x;
        int g = (int)pb.y;
        float di2 = di * di;
        float yv = di * a2 + di2 * y1[gi];   // (A_hat^2 x)_i incl. self-loop
        float zv = di * az + di2;            // (A_hat 1)_i incl. self-loop
        atomicAdd(&bins[g], yv);
        atomicAdd(&bins[N_GRAPHS + g], zv);
        atomicAdd(&bins[2 * N_GRAPHS + g], 1.0f);
    }
    __syncthreads();
    for (int k = t; k < 3 * N_GRAPHS; k += 256)
        if (bins[k] != 0.0f) atomicAdd(&gacc[k], bins[k]);
}

// ---------------- final --------------------------------------------------
__global__ void final_kernel(const float* W1, const float* b1, const float* W2,
                             const float* b2, const float* gacc, float* out) {
    int g = threadIdx.x;
    if (g >= N_GRAPHS) return;
    float w0 = 0.f, w1 = 0.f, c0 = 0.f, c1 = 0.f;
    for (int j = 0; j < 16; ++j) {
        float a = W2[2 * j], b = W2[2 * j + 1];
        w0 += W1[j] * a;  w1 += W1[j] * b;
        c0 += b1[j] * a;  c1 += b1[j] * b;
    }
    float sy  = gacc[g];
    float sz  = gacc[N_GRAPHS + g];
    float cnt = gacc[2 * N_GRAPHS + g];
    float inv = 1.0f / fmaxf(cnt, 1.0f);
    out[2 * g + 0] = (sy * w0 + sz * c0 + cnt * b2[0]) * inv;
    out[2 * g + 1] = (sy * w1 + sz * c1 + cnt * b2[1]) * inv;
}

extern "C" void kernel_launch(void* const* d_in, const int* in_sizes, int n_in,
                              void* d_out, int out_size, void* d_ws, size_t ws_size,
                              hipStream_t stream) {
    const float* x     = (const float*)d_in[0];
    const int*   ei    = (const int*)d_in[1];
    const int*   batch = (const int*)d_in[2];
    const float* W1    = (const float*)d_in[3];
    const float* b1    = (const float*)d_in[4];
    const float* W2    = (const float*)d_in[5];
    const float* b2    = (const float*)d_in[6];
    float* out = (float*)d_out;

    // ws: wx[N] | y1[N] | pbt[N]f2 | pyz[N]u32 | gacc[192] | flag[16] | copies
    float*    f    = (float*)d_ws;
    float*    wx   = f;
    float*    y1   = wx + N_NODES;
    float2*   pbt  = (float2*)(y1 + N_NODES);
    unsigned* pyz  = (unsigned*)(pbt + N_NODES);
    float*    gacc = (float*)(pyz + N_NODES);
    int*      flag = (int*)(gacc + 3 * N_GRAPHS);
    unsigned* copies = (unsigned*)(flag + 16);

    const long fixedB = (5L * N_NODES + 3 * N_GRAPHS + 16) * 4;
    long availB = (long)ws_size - fixedB;
    long CD = availB / NRDF;                // deg u8 copies
    if (CD > 256) CD = 256; if (CD < 8) CD = 8;
    long G1 = availB / (2L * LDSW * 4);     // acc1 copies per group
    if (G1 > 128) G1 = 128; if (G1 < 4) G1 = 4;
    long G2 = availB / (3L * NR3 * 4);      // acc2 copies per group
    if (G2 > 85) G2 = 85; if (G2 < 4) G2 = 4;

    setup_kernel<<<1, 256, 0, stream>>>(ei, flag, gacc);

    deg_scan<<<(int)CD, SCAN_BS, 0, stream>>>(ei, flag, (unsigned char*)copies);
    deg_merge<<<(N_NODES + 63) / 64, 256, 0, stream>>>(
        (const unsigned char*)copies, (int)CD, x, batch, flag, wx, pbt);

    acc1_scan<<<(int)(2 * G1), SCAN_BS, 0, stream>>>(ei, flag, wx, (int)G1, copies);
    acc1_merge<<<(N_NODES + 63) / 64, 256, 0, stream>>>(
        copies, (int)G1, wx, pbt, y1, pyz);

    acc2_scan<<<(int)(3 * G2), SCAN_BS, 0, stream>>>(ei, flag, pyz, (int)G2, copies);
    acc2_merge<<<(N_NODES + 63) / 64, 256, 0, stream>>>(
        copies, (int)G2, y1, pbt, gacc);

    final_kernel<<<1, 64, 0, stream>>>(W1, b1, W2, b2, gacc, out);
}

// Round 13
// 158.257 us; speedup vs baseline: 3.3244x; 1.0626x over previous
//
#include <hip/hip_runtime.h>

#define N_NODES  100000
#define N_EDGES  6400000
#define N_GRAPHS 64
#define SCAN_BS  1024
#define NRDF     100096              // deg: all nodes, u8 bins = 97.75 KB LDS
#define DEGW     (NRDF / 4)          // 25024 u32 words
#define NR2      50048               // acc1: nodes per block-group (2 groups)
#define LDSW     (NR2 / 2)           // 25024 u32 words (f16 pairs) = 97.75 KB
#define NR3      33344               // acc2: nodes per block-group (3 groups), 130.25 KB

// int64-layout detect: hi dwords of first 16 values all zero => stride 2.
__device__ __forceinline__ int idx_stride(const int* ei) {
    int allzero = 1;
    #pragma unroll
    for (int k = 0; k < 16; ++k)
        if (ei[2 * k + 1] != 0) allzero = 0;
    return allzero ? 2 : 1;
}

// ---------------- stage 1: degree, ONE scan, u8-packed LDS bins ----------
__global__ __launch_bounds__(SCAN_BS)
void deg_scan(const int* ei, unsigned char* copies) {
    __shared__ unsigned bins[DEGW];
    for (int i = threadIdx.x; i < DEGW; i += SCAN_BS) bins[i] = 0u;
    __syncthreads();
    const int stride = idx_stride(ei);
    const int tid = blockIdx.x * SCAN_BS + threadIdx.x;
    const int nth = gridDim.x * SCAN_BS;
#define DEGADD(u) { unsigned a = (unsigned)(u); \
    if (a < NRDF) atomicAdd(&bins[a >> 2], 1u << (8 * (a & 3))); }
    if (stride == 2) {                      // int64 dst col: 2 edges / int4
        const int4* dp = (const int4*)(ei + (size_t)N_EDGES * 2);
        const int lim = N_EDGES / 2;
        int q = tid;
        for (; q + 7 * nth < lim; q += 8 * nth) {
            int4 v0 = dp[q],           v1 = dp[q + nth];
            int4 v2 = dp[q + 2 * nth], v3 = dp[q + 3 * nth];
            int4 v4 = dp[q + 4 * nth], v5 = dp[q + 5 * nth];
            int4 v6 = dp[q + 6 * nth], v7 = dp[q + 7 * nth];
            DEGADD(v0.x); DEGADD(v0.z); DEGADD(v1.x); DEGADD(v1.z);
            DEGADD(v2.x); DEGADD(v2.z); DEGADD(v3.x); DEGADD(v3.z);
            DEGADD(v4.x); DEGADD(v4.z); DEGADD(v5.x); DEGADD(v5.z);
            DEGADD(v6.x); DEGADD(v6.z); DEGADD(v7.x); DEGADD(v7.z);
        }
        for (; q < lim; q += nth) { int4 v = dp[q]; DEGADD(v.x); DEGADD(v.z); }
    } else {                                // int32 dst col: 4 edges / int4
        const int4* dp = (const int4*)(ei + (size_t)N_EDGES);
        for (int q = tid; q < N_EDGES / 4; q += nth) {
            int4 v = dp[q];
            DEGADD(v.x); DEGADD(v.y); DEGADD(v.z); DEGADD(v.w);
        }
    }
#undef DEGADD
    __syncthreads();
    unsigned* my = (unsigned*)(copies + (size_t)blockIdx.x * NRDF);
    for (int i = threadIdx.x; i < DEGW; i += SCAN_BS) my[i] = bins[i];
}

// merge C u8 copies -> dinv; wx = dinv*x, pbt = (dinv, batch)
__global__ void deg_merge(const unsigned char* copies, int C, const int* ei,
                          const float* x, const int* batch,
                          float* wx, float2* pbt) {
    __shared__ float red[256];
    int il = threadIdx.x & 63, cs = threadIdx.x >> 6;
    int gi = blockIdx.x * 64 + il;
    bool ok = (gi < N_NODES);
    float partial = 0.0f;
    if (ok)
        for (int c = cs; c < C; c += 4)
            partial += (float)copies[(size_t)c * NRDF + gi];
    red[threadIdx.x] = partial;
    __syncthreads();
    if (cs == 0 && ok) {
        float d = 1.0f + red[il] + red[64 + il] + red[128 + il] + red[192 + il];
        float di = rsqrtf(d);
        wx[gi] = di * x[gi];
        const int stride = idx_stride(ei);
        pbt[gi] = make_float2(di, (float)batch[(size_t)gi * stride]);
    }
}

// ---------------- stage 2: acc1, 2 groups, f16 LDS bins ------------------
__device__ __forceinline__ void pk_add_f16(unsigned ldsBase, unsigned a, float v) {
    _Float16 h = (_Float16)v;
    unsigned hb = (unsigned)__builtin_bit_cast(unsigned short, h);
    unsigned pk = (a & 1) ? (hb << 16) : hb;
    unsigned addr = ldsBase + ((a >> 1) << 2);
    asm volatile("ds_pk_add_f16 %0, %1" :: "v"(addr), "v"(pk) : "memory");
}

__global__ __launch_bounds__(SCAN_BS)
void acc1_scan(const int* ei, const float* wx, int G, unsigned* copies) {
    __shared__ unsigned bins[LDSW];
    for (int i = threadIdx.x; i < LDSW; i += SCAN_BS) bins[i] = 0u;
    __syncthreads();
    const int grp = (blockIdx.x >= G) ? 1 : 0;
    const int lo = grp * NR2;
    const int lb = blockIdx.x - grp * G;
    const unsigned ldsBase = (unsigned)(uintptr_t)&bins[0];
    const int stride = idx_stride(ei);
    const int tid = lb * SCAN_BS + threadIdx.x;
    const int nth = G * SCAN_BS;            // per-group stride: covers ALL edges
    if (stride == 2) {
        const int4* sp = (const int4*)ei;
        const int4* dp = (const int4*)(ei + (size_t)N_EDGES * 2);
        const int lim = N_EDGES / 2;
        int q = tid;
        for (; q + 3 * nth < lim; q += 4 * nth) {
            int4 d0 = dp[q],           d1 = dp[q + nth];
            int4 d2 = dp[q + 2 * nth], d3 = dp[q + 3 * nth];
            int4 s0 = sp[q],           s1 = sp[q + nth];
            int4 s2 = sp[q + 2 * nth], s3 = sp[q + 3 * nth];
            unsigned a0 = (unsigned)(d0.x - lo), a1 = (unsigned)(d0.z - lo);
            unsigned a2 = (unsigned)(d1.x - lo), a3 = (unsigned)(d1.z - lo);
            unsigned a4 = (unsigned)(d2.x - lo), a5 = (unsigned)(d2.z - lo);
            unsigned a6 = (unsigned)(d3.x - lo), a7 = (unsigned)(d3.z - lo);
            float w0 = (a0 < NR2) ? wx[s0.x] : 0.0f;
            float w1 = (a1 < NR2) ? wx[s0.z] : 0.0f;
            float w2 = (a2 < NR2) ? wx[s1.x] : 0.0f;
            float w3 = (a3 < NR2) ? wx[s1.z] : 0.0f;
            float w4 = (a4 < NR2) ? wx[s2.x] : 0.0f;
            float w5 = (a5 < NR2) ? wx[s2.z] : 0.0f;
            float w6 = (a6 < NR2) ? wx[s3.x] : 0.0f;
            float w7 = (a7 < NR2) ? wx[s3.z] : 0.0f;
            if (a0 < NR2) pk_add_f16(ldsBase, a0, w0);
            if (a1 < NR2) pk_add_f16(ldsBase, a1, w1);
            if (a2 < NR2) pk_add_f16(ldsBase, a2, w2);
            if (a3 < NR2) pk_add_f16(ldsBase, a3, w3);
            if (a4 < NR2) pk_add_f16(ldsBase, a4, w4);
            if (a5 < NR2) pk_add_f16(ldsBase, a5, w5);
            if (a6 < NR2) pk_add_f16(ldsBase, a6, w6);
            if (a7 < NR2) pk_add_f16(ldsBase, a7, w7);
        }
        for (; q < lim; q += nth) {
            int4 dv = dp[q]; int4 sv = sp[q];
            unsigned a = (unsigned)(dv.x - lo), b = (unsigned)(dv.z - lo);
            if (a < NR2) pk_add_f16(ldsBase, a, wx[sv.x]);
            if (b < NR2) pk_add_f16(ldsBase, b, wx[sv.z]);
        }
    } else {
        const int4* sp = (const int4*)ei;
        const int4* dp = (const int4*)(ei + (size_t)N_EDGES);
        for (int q = tid; q < N_EDGES / 4; q += nth) {
            int4 dv = dp[q]; int4 sv = sp[q];
            unsigned a = (unsigned)(dv.x - lo), b = (unsigned)(dv.y - lo);
            unsigned c = (unsigned)(dv.z - lo), d = (unsigned)(dv.w - lo);
            if (a < NR2) pk_add_f16(ldsBase, a, wx[sv.x]);
            if (b < NR2) pk_add_f16(ldsBase, b, wx[sv.y]);
            if (c < NR2) pk_add_f16(ldsBase, c, wx[sv.z]);
            if (d < NR2) pk_add_f16(ldsBase, d, wx[sv.w]);
        }
    }
    __syncthreads();
    unsigned* my = copies + (size_t)blockIdx.x * LDSW;
    for (int i = threadIdx.x; i < LDSW; i += SCAN_BS) my[i] = bins[i];
}

// merge acc1 copies -> y1 (f32), pyz = packed (f16 dinv*y1, f16 dinv);
// block 0 also zeroes gacc (only acc2_merge accumulates it, strictly later).
__global__ void acc1_merge(const unsigned* copies, int G,
                           const float* wx, const float2* pbt,
                           float* y1, unsigned* pyz, float* gacc) {
    __shared__ float red[256];
    int t = threadIdx.x;
    if (blockIdx.x == 0 && t < 3 * N_GRAPHS) gacc[t] = 0.0f;
    int il = t & 63, cs = t >> 6;
    int gi = blockIdx.x * 64 + il;
    bool ok = (gi < N_NODES);
    float partial = 0.0f;
    int grp = (gi >= NR2) ? 1 : 0;
    int li  = gi - grp * NR2;
    if (ok) {
        int sh = 16 * (li & 1), w = li >> 1;
        const unsigned* base = copies + (size_t)grp * G * LDSW;
        for (int c = cs; c < G; c += 4) {
            unsigned u = (base[(size_t)c * LDSW + w] >> sh) & 0xFFFFu;
            partial += (float)__builtin_bit_cast(_Float16, (unsigned short)u);
        }
    }
    red[t] = partial;
    __syncthreads();
    if (cs == 0 && ok) {
        float a1 = red[il] + red[64 + il] + red[128 + il] + red[192 + il];
        float di = pbt[gi].x;
        float y1v = di * (a1 + wx[gi]);      // dinv*(acc1 + dinv*x)
        y1[gi] = y1v;
        _Float16 hy = (_Float16)(di * y1v);  // wy = dinv*y1
        _Float16 hz = (_Float16)di;          // wz = dinv
        pyz[gi] = (unsigned)__builtin_bit_cast(unsigned short, hy)
                | ((unsigned)__builtin_bit_cast(unsigned short, hz) << 16);
    }
}

// ---------------- stage 3: acc2/accz scatter, 3 groups -------------------
__global__ __launch_bounds__(SCAN_BS)
void acc2_scan(const int* ei, const unsigned* pyz, int G, unsigned* copies) {
    __shared__ unsigned bins[NR3];          // u32 = (f16 wy-sum, f16 wz-sum)
    for (int i = threadIdx.x; i < NR3; i += SCAN_BS) bins[i] = 0u;
    __syncthreads();
    const int grp = blockIdx.x / G;         // 0,1,2
    const int lo = grp * NR3;
    const int lb = blockIdx.x - grp * G;
    const unsigned ldsBase = (unsigned)(uintptr_t)&bins[0];
    const int stride = idx_stride(ei);
    const int tid = lb * SCAN_BS + threadIdx.x;
    const int nth = G * SCAN_BS;
#define PKW(addr_a, pk) asm volatile("ds_pk_add_f16 %0, %1" :: \
    "v"(ldsBase + ((addr_a) << 2)), "v"(pk) : "memory")
    if (stride == 2) {
        const int4* sp = (const int4*)ei;
        const int4* dp = (const int4*)(ei + (size_t)N_EDGES * 2);
        const int lim = N_EDGES / 2;
        int q = tid;
        for (; q + 3 * nth < lim; q += 4 * nth) {
            int4 d0 = dp[q],           d1 = dp[q + nth];
            int4 d2 = dp[q + 2 * nth], d3 = dp[q + 3 * nth];
            int4 s0 = sp[q],           s1 = sp[q + nth];
            int4 s2 = sp[q + 2 * nth], s3 = sp[q + 3 * nth];
            unsigned a0 = (unsigned)(d0.x - lo), a1 = (unsigned)(d0.z - lo);
            unsigned a2 = (unsigned)(d1.x - lo), a3 = (unsigned)(d1.z - lo);
            unsigned a4 = (unsigned)(d2.x - lo), a5 = (unsigned)(d2.z - lo);
            unsigned a6 = (unsigned)(d3.x - lo), a7 = (unsigned)(d3.z - lo);
            unsigned p0 = (a0 < NR3) ? pyz[s0.x] : 0u;
            unsigned p1 = (a1 < NR3) ? pyz[s0.z] : 0u;
            unsigned p2 = (a2 < NR3) ? pyz[s1.x] : 0u;
            unsigned p3 = (a3 < NR3) ? pyz[s1.z] : 0u;
            unsigned p4 = (a4 < NR3) ? pyz[s2.x] : 0u;
            unsigned p5 = (a5 < NR3) ? pyz[s2.z] : 0u;
            unsigned p6 = (a6 < NR3) ? pyz[s3.x] : 0u;
            unsigned p7 = (a7 < NR3) ? pyz[s3.z] : 0u;
            if (a0 < NR3) PKW(a0, p0);
            if (a1 < NR3) PKW(a1, p1);
            if (a2 < NR3) PKW(a2, p2);
            if (a3 < NR3) PKW(a3, p3);
            if (a4 < NR3) PKW(a4, p4);
            if (a5 < NR3) PKW(a5, p5);
            if (a6 < NR3) PKW(a6, p6);
            if (a7 < NR3) PKW(a7, p7);
        }
        for (; q < lim; q += nth) {
            int4 dv = dp[q]; int4 sv = sp[q];
            unsigned a = (unsigned)(dv.x - lo), b = (unsigned)(dv.z - lo);
            if (a < NR3) { unsigned p = pyz[sv.x]; PKW(a, p); }
            if (b < NR3) { unsigned p = pyz[sv.z]; PKW(b, p); }
        }
    } else {
        const int4* sp = (const int4*)ei;
        const int4* dp = (const int4*)(ei + (size_t)N_EDGES);
        for (int q = tid; q < N_EDGES / 4; q += nth) {
            int4 dv = dp[q]; int4 sv = sp[q];
            unsigned a = (unsigned)(dv.x - lo), b = (unsigned)(dv.y - lo);
            unsigned c = (unsigned)(dv.z - lo), d = (unsigned)(dv.w - lo);
            if (a < NR3) { unsigned p = pyz[sv.x]; PKW(a, p); }
            if (b < NR3) { unsigned p = pyz[sv.y]; PKW(b, p); }
            if (c < NR3) { unsigned p = pyz[sv.z]; PKW(c, p); }
            if (d < NR3) { unsigned p = pyz[sv.w]; PKW(d, p); }
        }
    }
#undef PKW
    __syncthreads();
    unsigned* my = copies + (size_t)blockIdx.x * NR3;
    for (int i = threadIdx.x; i < NR3; i += SCAN_BS) my[i] = bins[i];
}

// merge acc2 copies; pool Sy/Sz/count (incl. self-loop) into gacc
__global__ void acc2_merge(const unsigned* copies, int G,
                           const float* y1, const float2* pbt, float* gacc) {
    __shared__ float redY[256];
    __shared__ float redZ[256];
    __shared__ float bins[3 * N_GRAPHS];
    int t = threadIdx.x;
    for (int k = t; k < 3 * N_GRAPHS; k += 256) bins[k] = 0.0f;
    int il = t & 63, cs = t >> 6;
    int gi = blockIdx.x * 64 + il;
    bool ok = (gi < N_NODES);
    float pyv = 0.0f, pzv = 0.0f;
    if (ok) {
        int grp = gi / NR3;
        int li  = gi - grp * NR3;
        const unsigned* base = copies + (size_t)grp * G * NR3;
        for (int c = cs; c < G; c += 4) {
            unsigned u = base[(size_t)c * NR3 + li];
            pyv += (float)__builtin_bit_cast(_Float16, (unsigned short)(u & 0xFFFFu));
            pzv += (float)__builtin_bit_cast(_Float16, (unsigned short)(u >> 16));
        }
    }
    redY[t] = pyv;
    redZ[t] = pzv;
    __syncthreads();
    if (cs == 0 && ok) {
        float a2 = redY[il] + redY[64 + il] + redY[128 + il] + redY[192 + il];
        float az = redZ[il] + redZ[64 + il] + redZ[128 + il] + redZ[192 + il];
        float2 pb = pbt[gi];
        float di = pb.x;
        int g = (int)pb.y;
        float di2 = di * di;
        float yv = di * a2 + di2 * y1[gi];   // (A_hat^2 x)_i incl. self-loop
        float zv = di * az + di2;            // (A_hat 1)_i incl. self-loop
        atomicAdd(&bins[g], yv);
        atomicAdd(&bins[N_GRAPHS + g], zv);
        atomicAdd(&bins[2 * N_GRAPHS + g], 1.0f);
    }
    __syncthreads();
    for (int k = t; k < 3 * N_GRAPHS; k += 256)
        if (bins[k] != 0.0f) atomicAdd(&gacc[k], bins[k]);
}

// ---------------- final --------------------------------------------------
__global__ void final_kernel(const float* W1, const float* b1, const float* W2,
                             const float* b2, const float* gacc, float* out) {
    int g = threadIdx.x;
    if (g >= N_GRAPHS) return;
    float w0 = 0.f, w1 = 0.f, c0 = 0.f, c1 = 0.f;
    for (int j = 0; j < 16; ++j) {
        float a = W2[2 * j], b = W2[2 * j + 1];
        w0 += W1[j] * a;  w1 += W1[j] * b;
        c0 += b1[j] * a;  c1 += b1[j] * b;
    }
    float sy  = gacc[g];
    float sz  = gacc[N_GRAPHS + g];
    float cnt = gacc[2 * N_GRAPHS + g];
    float inv = 1.0f / fmaxf(cnt, 1.0f);
    out[2 * g + 0] = (sy * w0 + sz * c0 + cnt * b2[0]) * inv;
    out[2 * g + 1] = (sy * w1 + sz * c1 + cnt * b2[1]) * inv;
}

extern "C" void kernel_launch(void* const* d_in, const int* in_sizes, int n_in,
                              void* d_out, int out_size, void* d_ws, size_t ws_size,
                              hipStream_t stream) {
    const float* x     = (const float*)d_in[0];
    const int*   ei    = (const int*)d_in[1];
    const int*   batch = (const int*)d_in[2];
    const float* W1    = (const float*)d_in[3];
    const float* b1    = (const float*)d_in[4];
    const float* W2    = (const float*)d_in[5];
    const float* b2    = (const float*)d_in[6];
    float* out = (float*)d_out;

    // ws: wx[N] | y1[N] | pbt[N]f2 | pyz[N]u32 | gacc[192] | copies
    float*    f    = (float*)d_ws;
    float*    wx   = f;
    float*    y1   = wx + N_NODES;
    float2*   pbt  = (float2*)(y1 + N_NODES);
    unsigned* pyz  = (unsigned*)(pbt + N_NODES);
    float*    gacc = (float*)(pyz + N_NODES);
    unsigned* copies = (unsigned*)(gacc + 3 * N_GRAPHS + 16);

    const long fixedB = (5L * N_NODES + 3 * N_GRAPHS + 16) * 4;
    long availB = (long)ws_size - fixedB;
    long CD = availB / NRDF;                // deg u8 copies
    if (CD > 256) CD = 256; if (CD < 8) CD = 8;
    long G1 = availB / (2L * LDSW * 4);     // acc1 copies per group
    if (G1 > 128) G1 = 128; if (G1 < 4) G1 = 4;
    long G2 = availB / (3L * NR3 * 4);      // acc2 copies per group
    if (G2 > 85) G2 = 85; if (G2 < 4) G2 = 4;

    deg_scan<<<(int)CD, SCAN_BS, 0, stream>>>(ei, (unsigned char*)copies);
    deg_merge<<<(N_NODES + 63) / 64, 256, 0, stream>>>(
        (const unsigned char*)copies, (int)CD, ei, x, batch, wx, pbt);

    acc1_scan<<<(int)(2 * G1), SCAN_BS, 0, stream>>>(ei, wx, (int)G1, copies);
    acc1_merge<<<(N_NODES + 63) / 64, 256, 0, stream>>>(
        copies, (int)G1, wx, pbt, y1, pyz, gacc);

    acc2_scan<<<(int)(3 * G2), SCAN_BS, 0, stream>>>(ei, pyz, (int)G2, copies);
    acc2_merge<<<(N_NODES + 63) / 64, 256, 0, stream>>>(
        copies, (int)G2, y1, pbt, gacc);

    final_kernel<<<1, 64, 0, stream>>>(W1, b1, W2, b2, gacc, out);
}